// Round 5
// baseline (226.707 us; speedup 1.0000x reference)
//
#include <hip/hip_runtime.h>
#include <math.h>

#define H 16
#define S 2048
#define DM 1024
#define HD 64
// 0.125 (1/sqrt(64)) * log2(e): softmax computed in exp2 domain
#define QSCALE 0.18033688011112042f

typedef __attribute__((ext_vector_type(8))) short short8;
typedef __attribute__((ext_vector_type(4))) float f32x4;
typedef __attribute__((ext_vector_type(4))) unsigned short u16x4;
typedef __attribute__((ext_vector_type(2))) unsigned int uint2v;
#if __has_builtin(__builtin_amdgcn_cvt_pk_bf16_f32)
typedef __attribute__((ext_vector_type(2))) __bf16 bf16x2;
#endif

__device__ __forceinline__ unsigned short f2bf(float f) {
  unsigned int u = __builtin_bit_cast(unsigned int, f);
  u = (u + 0x7fffu + ((u >> 16) & 1u)) >> 16;
  return (unsigned short)u;
}

__device__ __forceinline__ unsigned int pk_bf16(float a, float b) {
#if __has_builtin(__builtin_amdgcn_cvt_pk_bf16_f32)
  bf16x2 r = __builtin_amdgcn_cvt_pk_bf16_f32(a, b);
  return __builtin_bit_cast(unsigned int, r);
#else
  return (unsigned int)f2bf(a) | ((unsigned int)f2bf(b) << 16);
#endif
}

__device__ __forceinline__ float fexp2(float x) {
#if __has_builtin(__builtin_amdgcn_exp2f)
  return __builtin_amdgcn_exp2f(x);
#else
  return exp2f(x);
#endif
}

__device__ __forceinline__ void async_ld16(const void* g, void* l) {
  __builtin_amdgcn_global_load_lds(
      (const __attribute__((address_space(1))) unsigned int*)g,
      (__attribute__((address_space(3))) unsigned int*)l, 16, 0, 0);
}

// ---------------------------------------------------------------------------
// Fused fp32->bf16 convert for all 3 inputs.
// Segments by linear block id: [0,4096) x, [4096,7168) qkv_w, [7168,8192) o_w.
// ---------------------------------------------------------------------------
__global__ void convert_all(const float* __restrict__ x, const float* __restrict__ w,
                            const float* __restrict__ ow,
                            unsigned short* __restrict__ xb,
                            unsigned short* __restrict__ wb,
                            unsigned short* __restrict__ owb) {
  int b = blockIdx.x;
  const f32x4* src;
  u16x4* dst;
  int idx;
  if (b < 4096) {
    src = (const f32x4*)x; dst = (u16x4*)xb; idx = b * 256 + threadIdx.x;
  } else if (b < 7168) {
    src = (const f32x4*)w; dst = (u16x4*)wb; idx = (b - 4096) * 256 + threadIdx.x;
  } else {
    src = (const f32x4*)ow; dst = (u16x4*)owb; idx = (b - 7168) * 256 + threadIdx.x;
  }
  f32x4 v = src[idx];
  u16x4 r;
  r.x = f2bf(v.x); r.y = f2bf(v.y); r.z = f2bf(v.z); r.w = f2bf(v.w);
  dst[idx] = r;
}

// ---------------------------------------------------------------------------
// GEMM 1 (R19): 128x128@3blk/CU K-loop (R18) + coalesced epilogue via MFMA
// operand swap. R18 post-mortem: K-loop upgrades (more MFMA/ds_read, +50%
// occupancy) were null -> epilogue-bound hypothesis. A wave's 64-col span
// b0 = col0+wn is 64-aligned -> b0%192 in {0,64,128} -> Q/K/V part is
// WAVE-UNIFORM. Q/K waves compute mfma(b,a) (transposed fragment: lane holds
// 4 consecutive d) -> one 8B uint2v store per tile (was 4 scalar 2B stores)
// + 2 cvt_pk (was 4 f2bf chains). V waves keep normal orientation (4
// consecutive s -> contiguous in V^T layout), pack via cvt_pk.
// ---------------------------------------------------------------------------
__global__ __launch_bounds__(256, 3) void gemm_qkv(
    const short* __restrict__ X, const short* __restrict__ W,
    unsigned short* __restrict__ qws, unsigned short* __restrict__ kws,
    unsigned short* __restrict__ vtws) {
  const int K = 1024;
  __shared__ __attribute__((aligned(16))) short As[128 * 64];
  __shared__ __attribute__((aligned(16))) short Bs[128 * 64];
  const int tid = threadIdx.x;
  const int w = tid >> 6, l = tid & 63, l15 = l & 15, quad = l >> 4;
  const int wm = (w >> 1) * 64, wn = (w & 1) * 64;
  const int row0 = blockIdx.y * 128, col0 = blockIdx.x * 128;

  // wave-uniform head/part decode of this wave's 64-wide column span
  const int b0 = col0 + wn;                // multiple of 64
  const int hh = b0 / 192;                 // head (uniform: 64-span in one part)
  const int part = (b0 - hh * 192) >> 6;   // 0=Q 1=K 2=V (uniform)
  const bool swp = (part < 2);             // transpose fragment for Q/K

  f32x4 zero = {0.f, 0.f, 0.f, 0.f};
  f32x4 acc[4][4];
  for (int i = 0; i < 4; ++i)
    for (int j = 0; j < 4; ++j) acc[i][j] = zero;

  const short* Ag = X + row0 * K;
  const short* Bg = W + col0 * K;

  for (int k0 = 0; k0 < K; k0 += 64) {
    __syncthreads();
    for (int i = 0; i < 4; ++i) {
      int u = i * 256 + tid;
      int r = u >> 3, c = u & 7;
      async_ld16(Ag + r * K + k0 + c * 8, As + u * 8);
    }
    for (int i = 0; i < 4; ++i) {
      int u = i * 256 + tid;
      int r = u >> 3, c = u & 7;
      async_ld16(Bg + r * K + k0 + c * 8, Bs + u * 8);
    }
    __syncthreads();
    for (int kk = 0; kk < 2; ++kk) {
      short8 a[4], b[4];
      for (int i = 0; i < 4; ++i)
        a[i] = *(const short8*)(As + (wm + i * 16 + l15) * 64 + kk * 32 + quad * 8);
      for (int j = 0; j < 4; ++j)
        b[j] = *(const short8*)(Bs + (wn + j * 16 + l15) * 64 + kk * 32 + quad * 8);
      if (swp) {
        for (int i = 0; i < 4; ++i)
          for (int j = 0; j < 4; ++j)
            acc[i][j] = __builtin_amdgcn_mfma_f32_16x16x32_bf16(b[j], a[i], acc[i][j], 0, 0, 0);
      } else {
        for (int i = 0; i < 4; ++i)
          for (int j = 0; j < 4; ++j)
            acc[i][j] = __builtin_amdgcn_mfma_f32_16x16x32_bf16(a[i], b[j], acc[i][j], 0, 0, 0);
      }
    }
  }

  if (swp) {
    // Transposed fragments: row(quad*4+reg) = e (4 consecutive d), col(l15) = s.
    unsigned short* dst = (part == 0) ? qws : kws;
    const float scale = (part == 0) ? QSCALE : 1.0f;
    for (int i = 0; i < 4; ++i) {
      int s = row0 + wm + i * 16 + l15;
      int n = s >> 11;
      s &= 2047;
      unsigned short* p = dst + ((n * H + hh) * S + s) * HD;
      for (int j = 0; j < 4; ++j) {
        int d = j * 16 + quad * 4;         // within-head dim, 4 consecutive
        f32x4 v = acc[i][j];
        uint2v pk;
        pk.x = pk_bf16(v.x * scale, v.y * scale);
        pk.y = pk_bf16(v.z * scale, v.w * scale);
        *(uint2v*)(p + d) = pk;
      }
    }
  } else {
    // Normal fragments: row(quad*4+reg) = s (4 consecutive), col(l15) = e.
    for (int i = 0; i < 4; ++i) {
      int s0 = row0 + wm + i * 16 + quad * 4;
      int n = s0 >> 11;
      s0 &= 2047;
      for (int j = 0; j < 4; ++j) {
        int d = j * 16 + l15;              // within-head dim
        f32x4 v = acc[i][j];
        uint2v pk;
        pk.x = pk_bf16(v.x, v.y);
        pk.y = pk_bf16(v.z, v.w);
        *(uint2v*)(vtws + ((n * H + hh) * HD + d) * S + s0) = pk;
      }
    }
  }
}

// ---------------------------------------------------------------------------
// Flash attention (R17-exact, best 58.2-58.4us): 8 waves x 16 q, XCD-affinity
// grid (FETCH 69.7->12.3MB verified). R18's setprio was null-to-negative ->
// removed. R15/R16/R17 refuted LDS-BW / intra-wave-chain / DMA-source
// theories; this structure is latency/issue-plateaued at ~58.4us.
// ---------------------------------------------------------------------------
__global__ __launch_bounds__(512, 4) void flash(
    const short* __restrict__ qws, const short* __restrict__ kws,
    const short* __restrict__ vtws, unsigned short* __restrict__ vals) {
  __shared__ __attribute__((aligned(16))) short Ks[2][128 * 64];
  __shared__ __attribute__((aligned(16))) short Vts[2][2][64 * 64];
  __shared__ __attribute__((aligned(16))) short Pt[8][16 * 64];
  const int tid = threadIdx.x;
  const int w = tid >> 6, l = tid & 63, l15 = l & 15, quad = l >> 4;
  // XCD-affinity decode: round-robin dispatch puts b on XCD b&7. Give each
  // XCD 4 whole (h,n) pairs (all 16 of their qb blocks).
  const int b = blockIdx.x;
  const int hn = (b & 7) * 4 + (b >> 7);   // 0..31
  const int qb = (b >> 3) & 15;
  const int h = hn & 15, n = hn >> 4;
  const int nh = n * H + h;
  const short* Qh = qws + nh * S * HD;
  const short* Kh = kws + nh * S * HD;
  const short* Vth = vtws + nh * HD * S;

  const int q0 = qb * 128 + w * 16;
  short8 qf[2];
  for (int c = 0; c < 2; ++c)
    qf[c] = *(const short8*)(Qh + (q0 + l15) * HD + c * 32 + quad * 8);

  // swizzled granule offsets (shorts) for fragment reads
  const int swz0 = ((4 * 0 + quad) ^ (l15 & 7)) * 8;
  const int swz1 = ((4 * 1 + quad) ^ (l15 & 7)) * 8;

  float lpart = 0.f;                       // per-lane partial of sum(exp2(s))
  f32x4 zero = {0.f, 0.f, 0.f, 0.f};
  f32x4 oacc[4] = {zero, zero, zero, zero};

  // DMA stage of one 128-step KV tile into buffer `buf` (swizzle via gather).
  // 512 threads x 2 chunks each for K (128 rows) and V (2x 64-kv sub-tiles).
  auto stage = [&](int kv0, int buf) {
    for (int i = 0; i < 2; ++i) {
      int u = i * 512 + tid;
      int r = u >> 3;
      int c = (u & 7) ^ (r & 7);
      async_ld16(Kh + (kv0 + r) * HD + c * 8, &Ks[buf][u * 8]);
    }
    for (int i = 0; i < 2; ++i) {
      int v = tid;                         // within-sub-tile chunk id
      int r = v >> 3;                      // d-row 0..63
      int c = (v & 7) ^ (r & 7);
      async_ld16(Vth + r * S + kv0 + i * 64 + c * 8, &Vts[buf][i][v * 8]);
    }
  };

  stage(0, 0);
  for (int t = 0; t < 16; ++t) {
    const int buf = t & 1;
    __syncthreads();                       // drains DMA for tile t; frees buf^1
    if (t < 15) stage((t + 1) * 128, buf ^ 1);

    for (int ss = 0; ss < 2; ++ss) {
      const short* Kb = &Ks[buf][ss * 64 * 64];
      const short* Vb = Vts[buf][ss];

      f32x4 sacc[4] = {zero, zero, zero, zero};
      {
        short8 kf[4];
        for (int i = 0; i < 4; ++i)
          kf[i] = *(const short8*)(Kb + (i * 16 + l15) * 64 + swz0);
        for (int i = 0; i < 4; ++i)
          sacc[i] = __builtin_amdgcn_mfma_f32_16x16x32_bf16(kf[i], qf[0], sacc[i], 0, 0, 0);
        for (int i = 0; i < 4; ++i)
          kf[i] = *(const short8*)(Kb + (i * 16 + l15) * 64 + swz1);
        for (int i = 0; i < 4; ++i)
          sacc[i] = __builtin_amdgcn_mfma_f32_16x16x32_bf16(kf[i], qf[1], sacc[i], 0, 0, 0);
      }

      // static-max softmax: p = 2^s; per-lane partial sum only
      for (int i = 0; i < 4; ++i) {
        f32x4 p;
        p.x = fexp2(sacc[i].x);
        p.y = fexp2(sacc[i].y);
        p.z = fexp2(sacc[i].z);
        p.w = fexp2(sacc[i].w);
        sacc[i] = p;
        lpart += p.x + p.y + p.z + p.w;
      }

      // P^T (C-layout) -> wave-private LDS [q=l15][kv], swizzled
      for (int i = 0; i < 4; ++i) {
        int g = 2 * i + (quad >> 1);
        uint2v pk;
        pk.x = pk_bf16(sacc[i].x, sacc[i].y);
        pk.y = pk_bf16(sacc[i].z, sacc[i].w);
        *(uint2v*)(&Pt[w][l15 * 64 + ((g ^ (l15 & 7)) * 8) + (quad & 1) * 4]) = pk;
      }
      asm volatile("s_waitcnt lgkmcnt(0)" ::: "memory");  // wave-private RAW

      {
        short8 vf[4];
        short8 pf0 = *(const short8*)(&Pt[w][l15 * 64 + swz0]);
        short8 pf1 = *(const short8*)(&Pt[w][l15 * 64 + swz1]);
        for (int i = 0; i < 4; ++i)
          vf[i] = *(const short8*)(Vb + (i * 16 + l15) * 64 + swz0);
        for (int i = 0; i < 4; ++i)
          oacc[i] = __builtin_amdgcn_mfma_f32_16x16x32_bf16(vf[i], pf0, oacc[i], 0, 0, 0);
        for (int i = 0; i < 4; ++i)
          vf[i] = *(const short8*)(Vb + (i * 16 + l15) * 64 + swz1);
        for (int i = 0; i < 4; ++i)
          oacc[i] = __builtin_amdgcn_mfma_f32_16x16x32_bf16(vf[i], pf1, oacc[i], 0, 0, 0);
      }
    }
  }

  // final row-sum across quads, then O^T[d][q] / l -> vals[n][s][h*64+d]
  float lrun = lpart;
  lrun += __shfl_xor(lrun, 16);
  lrun += __shfl_xor(lrun, 32);
  float inv = 1.0f / lrun;
  int s = q0 + l15;
  for (int i = 0; i < 4; ++i) {
    uint2v pk;
    pk.x = pk_bf16(oacc[i].x * inv, oacc[i].y * inv);
    pk.y = pk_bf16(oacc[i].z * inv, oacc[i].w * inv);
    *(uint2v*)(vals + (n * S + s) * DM + h * HD + i * 16 + quad * 4) = pk;
  }
}

// ---------------------------------------------------------------------------
// GEMM 3 (R19): out = vals @ o_w^T, FP32 output. 128x64 tile, grid 16x32 =
// 512 blocks = 2/CU. All cells computed with swapped operands -> lane holds
// 4 consecutive e -> one f32x4 16B store per tile (was 4 scalar dword
// stores).
// ---------------------------------------------------------------------------
__global__ __launch_bounds__(256, 2) void gemm_out(
    const short* __restrict__ A, const short* __restrict__ W,
    float* __restrict__ out) {
  const int K = 1024;
  __shared__ __attribute__((aligned(16))) short As[128 * 64];
  __shared__ __attribute__((aligned(16))) short Bs[64 * 64];
  const int tid = threadIdx.x;
  const int w = tid >> 6, l = tid & 63, l15 = l & 15, quad = l >> 4;
  const int wm = (w >> 1) * 64, wn = (w & 1) * 32;
  const int row0 = blockIdx.y * 128, col0 = blockIdx.x * 64;

  f32x4 zero = {0.f, 0.f, 0.f, 0.f};
  f32x4 acc[4][2];
  for (int i = 0; i < 4; ++i)
    for (int j = 0; j < 2; ++j) acc[i][j] = zero;

  const short* Ag = A + row0 * K;
  const short* Bg = W + col0 * K;

  for (int k0 = 0; k0 < K; k0 += 64) {
    __syncthreads();
    for (int i = 0; i < 4; ++i) {
      int u = i * 256 + tid;
      int r = u >> 3, c = u & 7;
      async_ld16(Ag + r * K + k0 + c * 8, As + u * 8);
    }
    for (int i = 0; i < 2; ++i) {
      int u = i * 256 + tid;
      int r = u >> 3, c = u & 7;
      async_ld16(Bg + r * K + k0 + c * 8, Bs + u * 8);
    }
    __syncthreads();
    for (int kk = 0; kk < 2; ++kk) {
      short8 a[4], b[2];
      for (int i = 0; i < 4; ++i)
        a[i] = *(const short8*)(As + (wm + i * 16 + l15) * 64 + kk * 32 + quad * 8);
      for (int j = 0; j < 2; ++j)
        b[j] = *(const short8*)(Bs + (wn + j * 16 + l15) * 64 + kk * 32 + quad * 8);
      for (int i = 0; i < 4; ++i)
        for (int j = 0; j < 2; ++j)
          acc[i][j] = __builtin_amdgcn_mfma_f32_16x16x32_bf16(b[j], a[i], acc[i][j], 0, 0, 0);
    }
  }

  // Swapped fragments: row(quad*4+reg) = e (4 consecutive), col(l15) = s.
  for (int i = 0; i < 4; ++i) {
    int s = row0 + wm + i * 16 + l15;
    for (int j = 0; j < 2; ++j) {
      int e0 = col0 + wn + j * 16 + quad * 4;
      *(f32x4*)(out + s * 1024 + e0) = acc[i][j];
    }
  }
}

extern "C" void kernel_launch(void* const* d_in, const int* in_sizes, int n_in,
                              void* d_out, int out_size, void* d_ws, size_t ws_size,
                              hipStream_t stream) {
  const float* x = (const float*)d_in[0];      // (2, 2048, 1024) fp32
  const float* qkv_w = (const float*)d_in[1];  // (3072, 1024) fp32
  const float* o_w = (const float*)d_in[2];    // (1024, 1024) fp32
  float* out = (float*)d_out;                  // fp32

  char* ws = (char*)d_ws;
  unsigned short* xb   = (unsigned short*)(ws);                   // [0, 8M)
  unsigned short* wb   = (unsigned short*)(ws + (8ull << 20));    // [8M, 14M)
  unsigned short* owb  = (unsigned short*)(ws + (14ull << 20));   // [14M, 16M)
  unsigned short* qws  = (unsigned short*)(ws + (16ull << 20));   // [16M, 24M)
  unsigned short* kws  = (unsigned short*)(ws + (24ull << 20));   // [24M, 32M)
  unsigned short* vtws = (unsigned short*)(ws + (32ull << 20));   // [32M, 40M)
  unsigned short* vals = xb;  // alias: xb dead after gemm_qkv

  convert_all<<<8192, 256, 0, stream>>>(x, qkv_w, o_w, xb, wb, owb);
  gemm_qkv<<<dim3(24, 32), 256, 0, stream>>>(
      (const short*)xb, (const short*)wb, qws, kws, vtws);
  flash<<<512, 512, 0, stream>>>(
      (const short*)qws, (const short*)kws, (const short*)vtws, vals);
  gemm_out<<<dim3(16, 32), 256, 0, stream>>>(
      (const short*)vals, (const short*)owb, out);
}

// Round 6
// 222.711 us; speedup vs baseline: 1.0179x; 1.0179x over previous
//
#include <hip/hip_runtime.h>
#include <math.h>

#define H 16
#define S 2048
#define DM 1024
#define HD 64
// 0.125 (1/sqrt(64)) * log2(e): softmax computed in exp2 domain
#define QSCALE 0.18033688011112042f

typedef __attribute__((ext_vector_type(8))) short short8;
typedef __attribute__((ext_vector_type(4))) float f32x4;
typedef __attribute__((ext_vector_type(4))) unsigned short u16x4;
typedef __attribute__((ext_vector_type(2))) unsigned int uint2v;
#if __has_builtin(__builtin_amdgcn_cvt_pk_bf16_f32)
typedef __attribute__((ext_vector_type(2))) __bf16 bf16x2;
#endif

__device__ __forceinline__ unsigned short f2bf(float f) {
  unsigned int u = __builtin_bit_cast(unsigned int, f);
  u = (u + 0x7fffu + ((u >> 16) & 1u)) >> 16;
  return (unsigned short)u;
}

__device__ __forceinline__ unsigned int pk_bf16(float a, float b) {
#if __has_builtin(__builtin_amdgcn_cvt_pk_bf16_f32)
  bf16x2 r = __builtin_amdgcn_cvt_pk_bf16_f32(a, b);
  return __builtin_bit_cast(unsigned int, r);
#else
  return (unsigned int)f2bf(a) | ((unsigned int)f2bf(b) << 16);
#endif
}

__device__ __forceinline__ float fexp2(float x) {
#if __has_builtin(__builtin_amdgcn_exp2f)
  return __builtin_amdgcn_exp2f(x);
#else
  return exp2f(x);
#endif
}

__device__ __forceinline__ void async_ld16(const void* g, void* l) {
  __builtin_amdgcn_global_load_lds(
      (const __attribute__((address_space(1))) unsigned int*)g,
      (__attribute__((address_space(3))) unsigned int*)l, 16, 0, 0);
}

// ---------------------------------------------------------------------------
// Fused fp32->bf16 convert for all 3 inputs.
// Segments by linear block id: [0,4096) x, [4096,7168) qkv_w, [7168,8192) o_w.
// ---------------------------------------------------------------------------
__global__ void convert_all(const float* __restrict__ x, const float* __restrict__ w,
                            const float* __restrict__ ow,
                            unsigned short* __restrict__ xb,
                            unsigned short* __restrict__ wb,
                            unsigned short* __restrict__ owb) {
  int b = blockIdx.x;
  const f32x4* src;
  u16x4* dst;
  int idx;
  if (b < 4096) {
    src = (const f32x4*)x; dst = (u16x4*)xb; idx = b * 256 + threadIdx.x;
  } else if (b < 7168) {
    src = (const f32x4*)w; dst = (u16x4*)wb; idx = (b - 4096) * 256 + threadIdx.x;
  } else {
    src = (const f32x4*)ow; dst = (u16x4*)owb; idx = (b - 7168) * 256 + threadIdx.x;
  }
  f32x4 v = src[idx];
  u16x4 r;
  r.x = f2bf(v.x); r.y = f2bf(v.y); r.z = f2bf(v.z); r.w = f2bf(v.w);
  dst[idx] = r;
}

// ---------------------------------------------------------------------------
// GEMM 1 (R20): 128x128@3blk/CU K-loop. R19 post-mortem: coalescing is about
// contiguity ACROSS LANES, not per-lane width. Old scalar Q/K scatter was
// already lane-coalesced (l15 lanes cover 32B segments); R19's swapped Q/K
// 8B/lane at 128B lane-stride was x8 write-amplified (WRITE_SIZE 145MB,
// 82us, HBM-write-bound). But the same counter exposed the OLD V^T path:
// 8B/lane at 4KB lane-stride = x8 amplification on 8MB. Fix = opposite of
// R19: Q/K normal (R18-exact scatter), V waves SWAP mfma operands so
// l15 <-> s: V^T stores become 32B lane-contiguous (x2 instead of x8).
// Part is wave-uniform (64-aligned wave col span, 64|192 alignment).
// ---------------------------------------------------------------------------
__global__ __launch_bounds__(256, 3) void gemm_qkv(
    const short* __restrict__ X, const short* __restrict__ W,
    unsigned short* __restrict__ qws, unsigned short* __restrict__ kws,
    unsigned short* __restrict__ vtws) {
  const int K = 1024;
  __shared__ __attribute__((aligned(16))) short As[128 * 64];
  __shared__ __attribute__((aligned(16))) short Bs[128 * 64];
  const int tid = threadIdx.x;
  const int w = tid >> 6, l = tid & 63, l15 = l & 15, quad = l >> 4;
  const int wm = (w >> 1) * 64, wn = (w & 1) * 64;
  const int row0 = blockIdx.y * 128, col0 = blockIdx.x * 128;

  // wave-uniform head/part decode of this wave's 64-wide column span
  const int b0 = col0 + wn;                // multiple of 64
  const int hh = b0 / 192;                 // head (uniform: 64-span in one part)
  const int part = (b0 - hh * 192) >> 6;   // 0=Q 1=K 2=V (uniform)
  const bool swp = (part == 2);            // transpose fragment for V only

  f32x4 zero = {0.f, 0.f, 0.f, 0.f};
  f32x4 acc[4][4];
  for (int i = 0; i < 4; ++i)
    for (int j = 0; j < 4; ++j) acc[i][j] = zero;

  const short* Ag = X + row0 * K;
  const short* Bg = W + col0 * K;

  for (int k0 = 0; k0 < K; k0 += 64) {
    __syncthreads();
    for (int i = 0; i < 4; ++i) {
      int u = i * 256 + tid;
      int r = u >> 3, c = u & 7;
      async_ld16(Ag + r * K + k0 + c * 8, As + u * 8);
    }
    for (int i = 0; i < 4; ++i) {
      int u = i * 256 + tid;
      int r = u >> 3, c = u & 7;
      async_ld16(Bg + r * K + k0 + c * 8, Bs + u * 8);
    }
    __syncthreads();
    for (int kk = 0; kk < 2; ++kk) {
      short8 a[4], b[4];
      for (int i = 0; i < 4; ++i)
        a[i] = *(const short8*)(As + (wm + i * 16 + l15) * 64 + kk * 32 + quad * 8);
      for (int j = 0; j < 4; ++j)
        b[j] = *(const short8*)(Bs + (wn + j * 16 + l15) * 64 + kk * 32 + quad * 8);
      if (swp) {
        for (int i = 0; i < 4; ++i)
          for (int j = 0; j < 4; ++j)
            acc[i][j] = __builtin_amdgcn_mfma_f32_16x16x32_bf16(b[j], a[i], acc[i][j], 0, 0, 0);
      } else {
        for (int i = 0; i < 4; ++i)
          for (int j = 0; j < 4; ++j)
            acc[i][j] = __builtin_amdgcn_mfma_f32_16x16x32_bf16(a[i], b[j], acc[i][j], 0, 0, 0);
      }
    }
  }

  if (!swp) {
    // Q/K normal fragments: row(quad*4+reg) = s (4 consecutive), col(l15) = d.
    // l15 lanes cover 32B contiguous per scalar store (lane-coalesced).
    unsigned short* dst = (part == 0) ? qws : kws;
    const float scale = (part == 0) ? QSCALE : 1.0f;
    for (int i = 0; i < 4; ++i) {
      int rowb = row0 + wm + i * 16 + quad * 4;  // 4-aligned: same n for 4 rows
      int n = rowb >> 11, s = rowb & 2047;
      unsigned short* p = dst + ((n * H + hh) * S + s) * HD;
      for (int j = 0; j < 4; ++j) {
        int d = j * 16 + l15;
        f32x4 v = acc[i][j];
        p[d] = f2bf(v.x * scale);
        p[d + HD] = f2bf(v.y * scale);
        p[d + 2 * HD] = f2bf(v.z * scale);
        p[d + 3 * HD] = f2bf(v.w * scale);
      }
    }
  } else {
    // V swapped fragments: row(quad*4+reg) = d (4 consecutive), col(l15) = s.
    // V^T[d][s] store: l15 lanes -> s consecutive = 32B contiguous segments.
    for (int i = 0; i < 4; ++i) {
      int s = row0 + wm + i * 16 + l15;
      int n = s >> 11;
      s &= 2047;
      unsigned short* p = vtws + (n * H + hh) * HD * S + s;
      for (int j = 0; j < 4; ++j) {
        int d = j * 16 + quad * 4;
        f32x4 v = acc[i][j];
        p[d * S] = f2bf(v.x);
        p[(d + 1) * S] = f2bf(v.y);
        p[(d + 2) * S] = f2bf(v.z);
        p[(d + 3) * S] = f2bf(v.w);
      }
    }
  }
}

// ---------------------------------------------------------------------------
// Flash attention (R17-exact, best 58.2-58.4us): 8 waves x 16 q, XCD-affinity
// grid (FETCH 69.7->12.3MB verified). R18's setprio was null-to-negative ->
// removed. R15/R16/R17 refuted LDS-BW / intra-wave-chain / DMA-source
// theories; this structure is latency/issue-plateaued at ~58.4us.
// ---------------------------------------------------------------------------
__global__ __launch_bounds__(512, 4) void flash(
    const short* __restrict__ qws, const short* __restrict__ kws,
    const short* __restrict__ vtws, unsigned short* __restrict__ vals) {
  __shared__ __attribute__((aligned(16))) short Ks[2][128 * 64];
  __shared__ __attribute__((aligned(16))) short Vts[2][2][64 * 64];
  __shared__ __attribute__((aligned(16))) short Pt[8][16 * 64];
  const int tid = threadIdx.x;
  const int w = tid >> 6, l = tid & 63, l15 = l & 15, quad = l >> 4;
  // XCD-affinity decode: round-robin dispatch puts b on XCD b&7. Give each
  // XCD 4 whole (h,n) pairs (all 16 of their qb blocks).
  const int b = blockIdx.x;
  const int hn = (b & 7) * 4 + (b >> 7);   // 0..31
  const int qb = (b >> 3) & 15;
  const int h = hn & 15, n = hn >> 4;
  const int nh = n * H + h;
  const short* Qh = qws + nh * S * HD;
  const short* Kh = kws + nh * S * HD;
  const short* Vth = vtws + nh * HD * S;

  const int q0 = qb * 128 + w * 16;
  short8 qf[2];
  for (int c = 0; c < 2; ++c)
    qf[c] = *(const short8*)(Qh + (q0 + l15) * HD + c * 32 + quad * 8);

  // swizzled granule offsets (shorts) for fragment reads
  const int swz0 = ((4 * 0 + quad) ^ (l15 & 7)) * 8;
  const int swz1 = ((4 * 1 + quad) ^ (l15 & 7)) * 8;

  float lpart = 0.f;                       // per-lane partial of sum(exp2(s))
  f32x4 zero = {0.f, 0.f, 0.f, 0.f};
  f32x4 oacc[4] = {zero, zero, zero, zero};

  // DMA stage of one 128-step KV tile into buffer `buf` (swizzle via gather).
  // 512 threads x 2 chunks each for K (128 rows) and V (2x 64-kv sub-tiles).
  auto stage = [&](int kv0, int buf) {
    for (int i = 0; i < 2; ++i) {
      int u = i * 512 + tid;
      int r = u >> 3;
      int c = (u & 7) ^ (r & 7);
      async_ld16(Kh + (kv0 + r) * HD + c * 8, &Ks[buf][u * 8]);
    }
    for (int i = 0; i < 2; ++i) {
      int v = tid;                         // within-sub-tile chunk id
      int r = v >> 3;                      // d-row 0..63
      int c = (v & 7) ^ (r & 7);
      async_ld16(Vth + r * S + kv0 + i * 64 + c * 8, &Vts[buf][i][v * 8]);
    }
  };

  stage(0, 0);
  for (int t = 0; t < 16; ++t) {
    const int buf = t & 1;
    __syncthreads();                       // drains DMA for tile t; frees buf^1
    if (t < 15) stage((t + 1) * 128, buf ^ 1);

    for (int ss = 0; ss < 2; ++ss) {
      const short* Kb = &Ks[buf][ss * 64 * 64];
      const short* Vb = Vts[buf][ss];

      f32x4 sacc[4] = {zero, zero, zero, zero};
      {
        short8 kf[4];
        for (int i = 0; i < 4; ++i)
          kf[i] = *(const short8*)(Kb + (i * 16 + l15) * 64 + swz0);
        for (int i = 0; i < 4; ++i)
          sacc[i] = __builtin_amdgcn_mfma_f32_16x16x32_bf16(kf[i], qf[0], sacc[i], 0, 0, 0);
        for (int i = 0; i < 4; ++i)
          kf[i] = *(const short8*)(Kb + (i * 16 + l15) * 64 + swz1);
        for (int i = 0; i < 4; ++i)
          sacc[i] = __builtin_amdgcn_mfma_f32_16x16x32_bf16(kf[i], qf[1], sacc[i], 0, 0, 0);
      }

      // static-max softmax: p = 2^s; per-lane partial sum only
      for (int i = 0; i < 4; ++i) {
        f32x4 p;
        p.x = fexp2(sacc[i].x);
        p.y = fexp2(sacc[i].y);
        p.z = fexp2(sacc[i].z);
        p.w = fexp2(sacc[i].w);
        sacc[i] = p;
        lpart += p.x + p.y + p.z + p.w;
      }

      // P^T (C-layout) -> wave-private LDS [q=l15][kv], swizzled
      for (int i = 0; i < 4; ++i) {
        int g = 2 * i + (quad >> 1);
        uint2v pk;
        pk.x = pk_bf16(sacc[i].x, sacc[i].y);
        pk.y = pk_bf16(sacc[i].z, sacc[i].w);
        *(uint2v*)(&Pt[w][l15 * 64 + ((g ^ (l15 & 7)) * 8) + (quad & 1) * 4]) = pk;
      }
      asm volatile("s_waitcnt lgkmcnt(0)" ::: "memory");  // wave-private RAW

      {
        short8 vf[4];
        short8 pf0 = *(const short8*)(&Pt[w][l15 * 64 + swz0]);
        short8 pf1 = *(const short8*)(&Pt[w][l15 * 64 + swz1]);
        for (int i = 0; i < 4; ++i)
          vf[i] = *(const short8*)(Vb + (i * 16 + l15) * 64 + swz0);
        for (int i = 0; i < 4; ++i)
          oacc[i] = __builtin_amdgcn_mfma_f32_16x16x32_bf16(vf[i], pf0, oacc[i], 0, 0, 0);
        for (int i = 0; i < 4; ++i)
          vf[i] = *(const short8*)(Vb + (i * 16 + l15) * 64 + swz1);
        for (int i = 0; i < 4; ++i)
          oacc[i] = __builtin_amdgcn_mfma_f32_16x16x32_bf16(vf[i], pf1, oacc[i], 0, 0, 0);
      }
    }
  }

  // final row-sum across quads, then O^T[d][q] / l -> vals[n][s][h*64+d]
  float lrun = lpart;
  lrun += __shfl_xor(lrun, 16);
  lrun += __shfl_xor(lrun, 32);
  float inv = 1.0f / lrun;
  int s = q0 + l15;
  for (int i = 0; i < 4; ++i) {
    uint2v pk;
    pk.x = pk_bf16(oacc[i].x * inv, oacc[i].y * inv);
    pk.y = pk_bf16(oacc[i].z * inv, oacc[i].w * inv);
    *(uint2v*)(vals + (n * S + s) * DM + h * HD + i * 16 + quad * 4) = pk;
  }
}

// ---------------------------------------------------------------------------
// GEMM 3 (R13-exact, reverted from R19's f32x4 store which was x4
// write-amplified — lanes at 4KB stride): out = vals @ o_w^T, FP32 output.
// 128x64 tile, grid 16x32 = 512 blocks = 2/CU. Scalar dword stores are
// lane-coalesced (l15 lanes cover 64B contiguous).
// ---------------------------------------------------------------------------
__global__ __launch_bounds__(256, 2) void gemm_out(
    const short* __restrict__ A, const short* __restrict__ W,
    float* __restrict__ out) {
  const int K = 1024;
  __shared__ __attribute__((aligned(16))) short As[128 * 64];
  __shared__ __attribute__((aligned(16))) short Bs[64 * 64];
  const int tid = threadIdx.x;
  const int w = tid >> 6, l = tid & 63, l15 = l & 15, quad = l >> 4;
  const int wm = (w >> 1) * 64, wn = (w & 1) * 32;
  const int row0 = blockIdx.y * 128, col0 = blockIdx.x * 64;

  f32x4 zero = {0.f, 0.f, 0.f, 0.f};
  f32x4 acc[4][2];
  for (int i = 0; i < 4; ++i)
    for (int j = 0; j < 2; ++j) acc[i][j] = zero;

  const short* Ag = A + row0 * K;
  const short* Bg = W + col0 * K;

  for (int k0 = 0; k0 < K; k0 += 64) {
    __syncthreads();
    for (int i = 0; i < 4; ++i) {
      int u = i * 256 + tid;
      int r = u >> 3, c = u & 7;
      async_ld16(Ag + r * K + k0 + c * 8, As + u * 8);
    }
    for (int i = 0; i < 2; ++i) {
      int u = i * 256 + tid;
      int r = u >> 3, c = u & 7;
      async_ld16(Bg + r * K + k0 + c * 8, Bs + u * 8);
    }
    __syncthreads();
    for (int kk = 0; kk < 2; ++kk) {
      short8 a[4], b[2];
      for (int i = 0; i < 4; ++i)
        a[i] = *(const short8*)(As + (wm + i * 16 + l15) * 64 + kk * 32 + quad * 8);
      for (int j = 0; j < 2; ++j)
        b[j] = *(const short8*)(Bs + (wn + j * 16 + l15) * 64 + kk * 32 + quad * 8);
      for (int i = 0; i < 4; ++i)
        for (int j = 0; j < 2; ++j)
          acc[i][j] = __builtin_amdgcn_mfma_f32_16x16x32_bf16(a[i], b[j], acc[i][j], 0, 0, 0);
    }
  }

  for (int i = 0; i < 4; ++i) {
    int rowb = row0 + wm + i * 16 + quad * 4;
    for (int j = 0; j < 2; ++j) {
      int e = col0 + wn + j * 16 + l15;
      f32x4 v = acc[i][j];
      out[(rowb + 0) * 1024 + e] = v.x;
      out[(rowb + 1) * 1024 + e] = v.y;
      out[(rowb + 2) * 1024 + e] = v.z;
      out[(rowb + 3) * 1024 + e] = v.w;
    }
  }
}

extern "C" void kernel_launch(void* const* d_in, const int* in_sizes, int n_in,
                              void* d_out, int out_size, void* d_ws, size_t ws_size,
                              hipStream_t stream) {
  const float* x = (const float*)d_in[0];      // (2, 2048, 1024) fp32
  const float* qkv_w = (const float*)d_in[1];  // (3072, 1024) fp32
  const float* o_w = (const float*)d_in[2];    // (1024, 1024) fp32
  float* out = (float*)d_out;                  // fp32

  char* ws = (char*)d_ws;
  unsigned short* xb   = (unsigned short*)(ws);                   // [0, 8M)
  unsigned short* wb   = (unsigned short*)(ws + (8ull << 20));    // [8M, 14M)
  unsigned short* owb  = (unsigned short*)(ws + (14ull << 20));   // [14M, 16M)
  unsigned short* qws  = (unsigned short*)(ws + (16ull << 20));   // [16M, 24M)
  unsigned short* kws  = (unsigned short*)(ws + (24ull << 20));   // [24M, 32M)
  unsigned short* vtws = (unsigned short*)(ws + (32ull << 20));   // [32M, 40M)
  unsigned short* vals = xb;  // alias: xb dead after gemm_qkv

  convert_all<<<8192, 256, 0, stream>>>(x, qkv_w, o_w, xb, wb, owb);
  gemm_qkv<<<dim3(24, 32), 256, 0, stream>>>(
      (const short*)xb, (const short*)wb, qws, kws, vtws);
  flash<<<512, 512, 0, stream>>>(
      (const short*)qws, (const short*)kws, (const short*)vtws, vals);
  gemm_out<<<dim3(16, 32), 256, 0, stream>>>(
      (const short*)vals, (const short*)owb, out);
}

// Round 7
// 180.578 us; speedup vs baseline: 1.2555x; 1.2333x over previous
//
#include <hip/hip_runtime.h>
#include <math.h>

#define H 16
#define S 2048
#define DM 1024
#define HD 64
// 0.125 (1/sqrt(64)) * log2(e): softmax computed in exp2 domain
#define QSCALE 0.18033688011112042f

typedef __attribute__((ext_vector_type(8))) short short8;
typedef __attribute__((ext_vector_type(4))) float f32x4;
typedef __attribute__((ext_vector_type(4))) unsigned short u16x4;
typedef __attribute__((ext_vector_type(2))) unsigned int uint2v;
#if __has_builtin(__builtin_amdgcn_cvt_pk_bf16_f32)
typedef __attribute__((ext_vector_type(2))) __bf16 bf16x2;
#endif

__device__ __forceinline__ unsigned short f2bf(float f) {
  unsigned int u = __builtin_bit_cast(unsigned int, f);
  u = (u + 0x7fffu + ((u >> 16) & 1u)) >> 16;
  return (unsigned short)u;
}

__device__ __forceinline__ unsigned int pk_bf16(float a, float b) {
#if __has_builtin(__builtin_amdgcn_cvt_pk_bf16_f32)
  bf16x2 r = __builtin_amdgcn_cvt_pk_bf16_f32(a, b);
  return __builtin_bit_cast(unsigned int, r);
#else
  return (unsigned int)f2bf(a) | ((unsigned int)f2bf(b) << 16);
#endif
}

__device__ __forceinline__ float fexp2(float x) {
#if __has_builtin(__builtin_amdgcn_exp2f)
  return __builtin_amdgcn_exp2f(x);
#else
  return exp2f(x);
#endif
}

__device__ __forceinline__ void async_ld16(const void* g, void* l) {
  __builtin_amdgcn_global_load_lds(
      (const __attribute__((address_space(1))) unsigned int*)g,
      (__attribute__((address_space(3))) unsigned int*)l, 16, 0, 0);
}

// ---------------------------------------------------------------------------
// Fused fp32->bf16 convert for all 3 inputs.
// Segments by linear block id: [0,4096) x, [4096,7168) qkv_w, [7168,8192) o_w.
// ---------------------------------------------------------------------------
__global__ void convert_all(const float* __restrict__ x, const float* __restrict__ w,
                            const float* __restrict__ ow,
                            unsigned short* __restrict__ xb,
                            unsigned short* __restrict__ wb,
                            unsigned short* __restrict__ owb) {
  int b = blockIdx.x;
  const f32x4* src;
  u16x4* dst;
  int idx;
  if (b < 4096) {
    src = (const f32x4*)x; dst = (u16x4*)xb; idx = b * 256 + threadIdx.x;
  } else if (b < 7168) {
    src = (const f32x4*)w; dst = (u16x4*)wb; idx = (b - 4096) * 256 + threadIdx.x;
  } else {
    src = (const f32x4*)ow; dst = (u16x4*)owb; idx = (b - 7168) * 256 + threadIdx.x;
  }
  f32x4 v = src[idx];
  u16x4 r;
  r.x = f2bf(v.x); r.y = f2bf(v.y); r.z = f2bf(v.z); r.w = f2bf(v.w);
  dst[idx] = r;
}

// ---------------------------------------------------------------------------
// GEMM 1 (R21): R18-exact structure restored (128x128@3blk/CU, normal mfma,
// per-(i,j) scatter epilogue — best measured total 183.3us). R19/R20's
// operand-swap epilogues both regressed (~80us, WRITE 145MB) for reasons the
// write-amplification model failed to predict twice — abandoned.
// New (one variable): T2 XOR-swizzled staging+reads, the exact pattern the
// flash kernel in this file already uses (stage source c^(r&7), read slot
// (granule)^(row&7)). Counter basis: SQ_LDS_BANK_CONFLICT 9.4M cyc (~37k/CU,
// ~38% of dispatch cycles) from 128B-stride ds_read_b128 on linear LDS.
// ---------------------------------------------------------------------------
__global__ __launch_bounds__(256, 3) void gemm_qkv(
    const short* __restrict__ X, const short* __restrict__ W,
    unsigned short* __restrict__ qws, unsigned short* __restrict__ kws,
    unsigned short* __restrict__ vtws) {
  const int K = 1024;
  __shared__ __attribute__((aligned(16))) short As[128 * 64];
  __shared__ __attribute__((aligned(16))) short Bs[128 * 64];
  const int tid = threadIdx.x;
  const int w = tid >> 6, l = tid & 63, l15 = l & 15, quad = l >> 4;
  const int wm = (w >> 1) * 64, wn = (w & 1) * 64;
  const int row0 = blockIdx.y * 128, col0 = blockIdx.x * 128;

  f32x4 zero = {0.f, 0.f, 0.f, 0.f};
  f32x4 acc[4][4];
  for (int i = 0; i < 4; ++i)
    for (int j = 0; j < 4; ++j) acc[i][j] = zero;

  const short* Ag = X + row0 * K;
  const short* Bg = W + col0 * K;

  // swizzled read slots: granule g at row r lives in LDS slot g^(r&7)
  const int rs = l15 & 7;

  for (int k0 = 0; k0 < K; k0 += 64) {
    __syncthreads();
    for (int i = 0; i < 4; ++i) {
      int u = i * 256 + tid;
      int r = u >> 3, c = (u & 7) ^ (r & 7);
      async_ld16(Ag + r * K + k0 + c * 8, As + u * 8);
    }
    for (int i = 0; i < 4; ++i) {
      int u = i * 256 + tid;
      int r = u >> 3, c = (u & 7) ^ (r & 7);
      async_ld16(Bg + r * K + k0 + c * 8, Bs + u * 8);
    }
    __syncthreads();
    for (int kk = 0; kk < 2; ++kk) {
      const int slot = ((kk * 4 + quad) ^ rs) * 8;
      short8 a[4], b[4];
      for (int i = 0; i < 4; ++i)
        a[i] = *(const short8*)(As + (wm + i * 16 + l15) * 64 + slot);
      for (int j = 0; j < 4; ++j)
        b[j] = *(const short8*)(Bs + (wn + j * 16 + l15) * 64 + slot);
      for (int i = 0; i < 4; ++i)
        for (int j = 0; j < 4; ++j)
          acc[i][j] = __builtin_amdgcn_mfma_f32_16x16x32_bf16(a[i], b[j], acc[i][j], 0, 0, 0);
    }
  }

  for (int i = 0; i < 4; ++i) {
    int rowb = row0 + wm + i * 16 + quad * 4;   // 4-aligned: same n for 4 rows
    int n = rowb >> 11, s = rowb & 2047;
    for (int j = 0; j < 4; ++j) {
      int e = col0 + wn + j * 16 + l15;
      int h = e / 192;
      int rem = e - h * 192;
      int part = rem >> 6, d = rem & 63;
      f32x4 v = acc[i][j];
      if (part == 0) {
        unsigned short* p = qws + ((n * H + h) * S + s) * HD + d;
        p[0] = f2bf(v.x * QSCALE);
        p[HD] = f2bf(v.y * QSCALE);
        p[2 * HD] = f2bf(v.z * QSCALE);
        p[3 * HD] = f2bf(v.w * QSCALE);
      } else if (part == 1) {
        unsigned short* p = kws + ((n * H + h) * S + s) * HD + d;
        p[0] = f2bf(v.x);
        p[HD] = f2bf(v.y);
        p[2 * HD] = f2bf(v.z);
        p[3 * HD] = f2bf(v.w);
      } else {
        u16x4 pk;
        pk.x = f2bf(v.x); pk.y = f2bf(v.y); pk.z = f2bf(v.z); pk.w = f2bf(v.w);
        *(u16x4*)(vtws + ((n * H + h) * HD + d) * S + s) = pk;
      }
    }
  }
}

// ---------------------------------------------------------------------------
// Flash attention (R17-exact, best 58.2-58.4us): 8 waves x 16 q, XCD-affinity
// grid (FETCH 69.7->12.3MB verified). setprio was null-to-negative (R18) ->
// removed. R15/R16/R17 refuted LDS-BW / intra-wave-chain / DMA-source
// theories; this structure is latency/issue-plateaued at ~58.4us (588 TF).
// ---------------------------------------------------------------------------
__global__ __launch_bounds__(512, 4) void flash(
    const short* __restrict__ qws, const short* __restrict__ kws,
    const short* __restrict__ vtws, unsigned short* __restrict__ vals) {
  __shared__ __attribute__((aligned(16))) short Ks[2][128 * 64];
  __shared__ __attribute__((aligned(16))) short Vts[2][2][64 * 64];
  __shared__ __attribute__((aligned(16))) short Pt[8][16 * 64];
  const int tid = threadIdx.x;
  const int w = tid >> 6, l = tid & 63, l15 = l & 15, quad = l >> 4;
  // XCD-affinity decode: round-robin dispatch puts b on XCD b&7. Give each
  // XCD 4 whole (h,n) pairs (all 16 of their qb blocks).
  const int b = blockIdx.x;
  const int hn = (b & 7) * 4 + (b >> 7);   // 0..31
  const int qb = (b >> 3) & 15;
  const int h = hn & 15, n = hn >> 4;
  const int nh = n * H + h;
  const short* Qh = qws + nh * S * HD;
  const short* Kh = kws + nh * S * HD;
  const short* Vth = vtws + nh * HD * S;

  const int q0 = qb * 128 + w * 16;
  short8 qf[2];
  for (int c = 0; c < 2; ++c)
    qf[c] = *(const short8*)(Qh + (q0 + l15) * HD + c * 32 + quad * 8);

  // swizzled granule offsets (shorts) for fragment reads
  const int swz0 = ((4 * 0 + quad) ^ (l15 & 7)) * 8;
  const int swz1 = ((4 * 1 + quad) ^ (l15 & 7)) * 8;

  float lpart = 0.f;                       // per-lane partial of sum(exp2(s))
  f32x4 zero = {0.f, 0.f, 0.f, 0.f};
  f32x4 oacc[4] = {zero, zero, zero, zero};

  // DMA stage of one 128-step KV tile into buffer `buf` (swizzle via gather).
  // 512 threads x 2 chunks each for K (128 rows) and V (2x 64-kv sub-tiles).
  auto stage = [&](int kv0, int buf) {
    for (int i = 0; i < 2; ++i) {
      int u = i * 512 + tid;
      int r = u >> 3;
      int c = (u & 7) ^ (r & 7);
      async_ld16(Kh + (kv0 + r) * HD + c * 8, &Ks[buf][u * 8]);
    }
    for (int i = 0; i < 2; ++i) {
      int v = tid;                         // within-sub-tile chunk id
      int r = v >> 3;                      // d-row 0..63
      int c = (v & 7) ^ (r & 7);
      async_ld16(Vth + r * S + kv0 + i * 64 + c * 8, &Vts[buf][i][v * 8]);
    }
  };

  stage(0, 0);
  for (int t = 0; t < 16; ++t) {
    const int buf = t & 1;
    __syncthreads();                       // drains DMA for tile t; frees buf^1
    if (t < 15) stage((t + 1) * 128, buf ^ 1);

    for (int ss = 0; ss < 2; ++ss) {
      const short* Kb = &Ks[buf][ss * 64 * 64];
      const short* Vb = Vts[buf][ss];

      f32x4 sacc[4] = {zero, zero, zero, zero};
      {
        short8 kf[4];
        for (int i = 0; i < 4; ++i)
          kf[i] = *(const short8*)(Kb + (i * 16 + l15) * 64 + swz0);
        for (int i = 0; i < 4; ++i)
          sacc[i] = __builtin_amdgcn_mfma_f32_16x16x32_bf16(kf[i], qf[0], sacc[i], 0, 0, 0);
        for (int i = 0; i < 4; ++i)
          kf[i] = *(const short8*)(Kb + (i * 16 + l15) * 64 + swz1);
        for (int i = 0; i < 4; ++i)
          sacc[i] = __builtin_amdgcn_mfma_f32_16x16x32_bf16(kf[i], qf[1], sacc[i], 0, 0, 0);
      }

      // static-max softmax: p = 2^s; per-lane partial sum only
      for (int i = 0; i < 4; ++i) {
        f32x4 p;
        p.x = fexp2(sacc[i].x);
        p.y = fexp2(sacc[i].y);
        p.z = fexp2(sacc[i].z);
        p.w = fexp2(sacc[i].w);
        sacc[i] = p;
        lpart += p.x + p.y + p.z + p.w;
      }

      // P^T (C-layout) -> wave-private LDS [q=l15][kv], swizzled
      for (int i = 0; i < 4; ++i) {
        int g = 2 * i + (quad >> 1);
        uint2v pk;
        pk.x = pk_bf16(sacc[i].x, sacc[i].y);
        pk.y = pk_bf16(sacc[i].z, sacc[i].w);
        *(uint2v*)(&Pt[w][l15 * 64 + ((g ^ (l15 & 7)) * 8) + (quad & 1) * 4]) = pk;
      }
      asm volatile("s_waitcnt lgkmcnt(0)" ::: "memory");  // wave-private RAW

      {
        short8 vf[4];
        short8 pf0 = *(const short8*)(&Pt[w][l15 * 64 + swz0]);
        short8 pf1 = *(const short8*)(&Pt[w][l15 * 64 + swz1]);
        for (int i = 0; i < 4; ++i)
          vf[i] = *(const short8*)(Vb + (i * 16 + l15) * 64 + swz0);
        for (int i = 0; i < 4; ++i)
          oacc[i] = __builtin_amdgcn_mfma_f32_16x16x32_bf16(vf[i], pf0, oacc[i], 0, 0, 0);
        for (int i = 0; i < 4; ++i)
          vf[i] = *(const short8*)(Vb + (i * 16 + l15) * 64 + swz1);
        for (int i = 0; i < 4; ++i)
          oacc[i] = __builtin_amdgcn_mfma_f32_16x16x32_bf16(vf[i], pf1, oacc[i], 0, 0, 0);
      }
    }
  }

  // final row-sum across quads, then O^T[d][q] / l -> vals[n][s][h*64+d]
  float lrun = lpart;
  lrun += __shfl_xor(lrun, 16);
  lrun += __shfl_xor(lrun, 32);
  float inv = 1.0f / lrun;
  int s = q0 + l15;
  for (int i = 0; i < 4; ++i) {
    uint2v pk;
    pk.x = pk_bf16(oacc[i].x * inv, oacc[i].y * inv);
    pk.y = pk_bf16(oacc[i].z * inv, oacc[i].w * inv);
    *(uint2v*)(vals + (n * S + s) * DM + h * HD + i * 16 + quad * 4) = pk;
  }
}

// ---------------------------------------------------------------------------
// GEMM 3 (R21): R13-exact structure (128x64 tile, 2/CU, lane-coalesced
// scalar epilogue) + T2 XOR-swizzled staging/reads (same pattern as above).
// ---------------------------------------------------------------------------
__global__ __launch_bounds__(256, 2) void gemm_out(
    const short* __restrict__ A, const short* __restrict__ W,
    float* __restrict__ out) {
  const int K = 1024;
  __shared__ __attribute__((aligned(16))) short As[128 * 64];
  __shared__ __attribute__((aligned(16))) short Bs[64 * 64];
  const int tid = threadIdx.x;
  const int w = tid >> 6, l = tid & 63, l15 = l & 15, quad = l >> 4;
  const int wm = (w >> 1) * 64, wn = (w & 1) * 32;
  const int row0 = blockIdx.y * 128, col0 = blockIdx.x * 64;

  f32x4 zero = {0.f, 0.f, 0.f, 0.f};
  f32x4 acc[4][2];
  for (int i = 0; i < 4; ++i)
    for (int j = 0; j < 2; ++j) acc[i][j] = zero;

  const short* Ag = A + row0 * K;
  const short* Bg = W + col0 * K;

  const int rs = l15 & 7;

  for (int k0 = 0; k0 < K; k0 += 64) {
    __syncthreads();
    for (int i = 0; i < 4; ++i) {
      int u = i * 256 + tid;
      int r = u >> 3, c = (u & 7) ^ (r & 7);
      async_ld16(Ag + r * K + k0 + c * 8, As + u * 8);
    }
    for (int i = 0; i < 2; ++i) {
      int u = i * 256 + tid;
      int r = u >> 3, c = (u & 7) ^ (r & 7);
      async_ld16(Bg + r * K + k0 + c * 8, Bs + u * 8);
    }
    __syncthreads();
    for (int kk = 0; kk < 2; ++kk) {
      const int slot = ((kk * 4 + quad) ^ rs) * 8;
      short8 a[4], b[2];
      for (int i = 0; i < 4; ++i)
        a[i] = *(const short8*)(As + (wm + i * 16 + l15) * 64 + slot);
      for (int j = 0; j < 2; ++j)
        b[j] = *(const short8*)(Bs + (wn + j * 16 + l15) * 64 + slot);
      for (int i = 0; i < 4; ++i)
        for (int j = 0; j < 2; ++j)
          acc[i][j] = __builtin_amdgcn_mfma_f32_16x16x32_bf16(a[i], b[j], acc[i][j], 0, 0, 0);
    }
  }

  for (int i = 0; i < 4; ++i) {
    int rowb = row0 + wm + i * 16 + quad * 4;
    for (int j = 0; j < 2; ++j) {
      int e = col0 + wn + j * 16 + l15;
      f32x4 v = acc[i][j];
      out[(rowb + 0) * 1024 + e] = v.x;
      out[(rowb + 1) * 1024 + e] = v.y;
      out[(rowb + 2) * 1024 + e] = v.z;
      out[(rowb + 3) * 1024 + e] = v.w;
    }
  }
}

extern "C" void kernel_launch(void* const* d_in, const int* in_sizes, int n_in,
                              void* d_out, int out_size, void* d_ws, size_t ws_size,
                              hipStream_t stream) {
  const float* x = (const float*)d_in[0];      // (2, 2048, 1024) fp32
  const float* qkv_w = (const float*)d_in[1];  // (3072, 1024) fp32
  const float* o_w = (const float*)d_in[2];    // (1024, 1024) fp32
  float* out = (float*)d_out;                  // fp32

  char* ws = (char*)d_ws;
  unsigned short* xb   = (unsigned short*)(ws);                   // [0, 8M)
  unsigned short* wb   = (unsigned short*)(ws + (8ull << 20));    // [8M, 14M)
  unsigned short* owb  = (unsigned short*)(ws + (14ull << 20));   // [14M, 16M)
  unsigned short* qws  = (unsigned short*)(ws + (16ull << 20));   // [16M, 24M)
  unsigned short* kws  = (unsigned short*)(ws + (24ull << 20));   // [24M, 32M)
  unsigned short* vtws = (unsigned short*)(ws + (32ull << 20));   // [32M, 40M)
  unsigned short* vals = xb;  // alias: xb dead after gemm_qkv

  convert_all<<<8192, 256, 0, stream>>>(x, qkv_w, o_w, xb, wb, owb);
  gemm_qkv<<<dim3(24, 32), 256, 0, stream>>>(
      (const short*)xb, (const short*)wb, qws, kws, vtws);
  flash<<<512, 512, 0, stream>>>(
      (const short*)qws, (const short*)kws, (const short*)vtws, vals);
  gemm_out<<<dim3(16, 32), 256, 0, stream>>>(
      (const short*)vals, (const short*)owb, out);
}

// Round 8
// 171.485 us; speedup vs baseline: 1.3220x; 1.0530x over previous
//
#include <hip/hip_runtime.h>
#include <math.h>

#define H 16
#define S 2048
#define DM 1024
#define HD 64
// 0.125 (1/sqrt(64)) * log2(e): softmax computed in exp2 domain
#define QSCALE 0.18033688011112042f

typedef __attribute__((ext_vector_type(8))) short short8;
typedef __attribute__((ext_vector_type(4))) float f32x4;
typedef __attribute__((ext_vector_type(4))) unsigned short u16x4;
typedef __attribute__((ext_vector_type(2))) unsigned int uint2v;
typedef __attribute__((ext_vector_type(4))) unsigned int uint4v;
#if __has_builtin(__builtin_amdgcn_cvt_pk_bf16_f32)
typedef __attribute__((ext_vector_type(2))) __bf16 bf16x2;
#endif

__device__ __forceinline__ unsigned short f2bf(float f) {
  unsigned int u = __builtin_bit_cast(unsigned int, f);
  u = (u + 0x7fffu + ((u >> 16) & 1u)) >> 16;
  return (unsigned short)u;
}

__device__ __forceinline__ unsigned int pk_bf16(float a, float b) {
#if __has_builtin(__builtin_amdgcn_cvt_pk_bf16_f32)
  bf16x2 r = __builtin_amdgcn_cvt_pk_bf16_f32(a, b);
  return __builtin_bit_cast(unsigned int, r);
#else
  return (unsigned int)f2bf(a) | ((unsigned int)f2bf(b) << 16);
#endif
}

__device__ __forceinline__ float fexp2(float x) {
#if __has_builtin(__builtin_amdgcn_exp2f)
  return __builtin_amdgcn_exp2f(x);
#else
  return exp2f(x);
#endif
}

__device__ __forceinline__ void async_ld16(const void* g, void* l) {
  __builtin_amdgcn_global_load_lds(
      (const __attribute__((address_space(1))) unsigned int*)g,
      (__attribute__((address_space(3))) unsigned int*)l, 16, 0, 0);
}

// ---------------------------------------------------------------------------
// Fused fp32->bf16 convert for all 3 inputs.
// Segments by linear block id: [0,4096) x, [4096,7168) qkv_w, [7168,8192) o_w.
// ---------------------------------------------------------------------------
__global__ void convert_all(const float* __restrict__ x, const float* __restrict__ w,
                            const float* __restrict__ ow,
                            unsigned short* __restrict__ xb,
                            unsigned short* __restrict__ wb,
                            unsigned short* __restrict__ owb) {
  int b = blockIdx.x;
  const f32x4* src;
  u16x4* dst;
  int idx;
  if (b < 4096) {
    src = (const f32x4*)x; dst = (u16x4*)xb; idx = b * 256 + threadIdx.x;
  } else if (b < 7168) {
    src = (const f32x4*)w; dst = (u16x4*)wb; idx = (b - 4096) * 256 + threadIdx.x;
  } else {
    src = (const f32x4*)ow; dst = (u16x4*)owb; idx = (b - 7168) * 256 + threadIdx.x;
  }
  f32x4 v = src[idx];
  u16x4 r;
  r.x = f2bf(v.x); r.y = f2bf(v.y); r.z = f2bf(v.z); r.w = f2bf(v.w);
  dst[idx] = r;
}

// ---------------------------------------------------------------------------
// GEMM 1 (R21-exact, best total): 128x128@3blk/CU, normal mfma, per-(i,j)
// scatter epilogue, T2 XOR-swizzled staging+reads.
// ---------------------------------------------------------------------------
__global__ __launch_bounds__(256, 3) void gemm_qkv(
    const short* __restrict__ X, const short* __restrict__ W,
    unsigned short* __restrict__ qws, unsigned short* __restrict__ kws,
    unsigned short* __restrict__ vtws) {
  const int K = 1024;
  __shared__ __attribute__((aligned(16))) short As[128 * 64];
  __shared__ __attribute__((aligned(16))) short Bs[128 * 64];
  const int tid = threadIdx.x;
  const int w = tid >> 6, l = tid & 63, l15 = l & 15, quad = l >> 4;
  const int wm = (w >> 1) * 64, wn = (w & 1) * 64;
  const int row0 = blockIdx.y * 128, col0 = blockIdx.x * 128;

  f32x4 zero = {0.f, 0.f, 0.f, 0.f};
  f32x4 acc[4][4];
  for (int i = 0; i < 4; ++i)
    for (int j = 0; j < 4; ++j) acc[i][j] = zero;

  const short* Ag = X + row0 * K;
  const short* Bg = W + col0 * K;

  // swizzled read slots: granule g at row r lives in LDS slot g^(r&7)
  const int rs = l15 & 7;

  for (int k0 = 0; k0 < K; k0 += 64) {
    __syncthreads();
    for (int i = 0; i < 4; ++i) {
      int u = i * 256 + tid;
      int r = u >> 3, c = (u & 7) ^ (r & 7);
      async_ld16(Ag + r * K + k0 + c * 8, As + u * 8);
    }
    for (int i = 0; i < 4; ++i) {
      int u = i * 256 + tid;
      int r = u >> 3, c = (u & 7) ^ (r & 7);
      async_ld16(Bg + r * K + k0 + c * 8, Bs + u * 8);
    }
    __syncthreads();
    for (int kk = 0; kk < 2; ++kk) {
      const int slot = ((kk * 4 + quad) ^ rs) * 8;
      short8 a[4], b[4];
      for (int i = 0; i < 4; ++i)
        a[i] = *(const short8*)(As + (wm + i * 16 + l15) * 64 + slot);
      for (int j = 0; j < 4; ++j)
        b[j] = *(const short8*)(Bs + (wn + j * 16 + l15) * 64 + slot);
      for (int i = 0; i < 4; ++i)
        for (int j = 0; j < 4; ++j)
          acc[i][j] = __builtin_amdgcn_mfma_f32_16x16x32_bf16(a[i], b[j], acc[i][j], 0, 0, 0);
    }
  }

  for (int i = 0; i < 4; ++i) {
    int rowb = row0 + wm + i * 16 + quad * 4;   // 4-aligned: same n for 4 rows
    int n = rowb >> 11, s = rowb & 2047;
    for (int j = 0; j < 4; ++j) {
      int e = col0 + wn + j * 16 + l15;
      int h = e / 192;
      int rem = e - h * 192;
      int part = rem >> 6, d = rem & 63;
      f32x4 v = acc[i][j];
      if (part == 0) {
        unsigned short* p = qws + ((n * H + h) * S + s) * HD + d;
        p[0] = f2bf(v.x * QSCALE);
        p[HD] = f2bf(v.y * QSCALE);
        p[2 * HD] = f2bf(v.z * QSCALE);
        p[3 * HD] = f2bf(v.w * QSCALE);
      } else if (part == 1) {
        unsigned short* p = kws + ((n * H + h) * S + s) * HD + d;
        p[0] = f2bf(v.x);
        p[HD] = f2bf(v.y);
        p[2 * HD] = f2bf(v.z);
        p[3 * HD] = f2bf(v.w);
      } else {
        u16x4 pk;
        pk.x = f2bf(v.x); pk.y = f2bf(v.y); pk.z = f2bf(v.z); pk.w = f2bf(v.w);
        *(u16x4*)(vtws + ((n * H + h) * HD + d) * S + s) = pk;
      }
    }
  }
}

// ---------------------------------------------------------------------------
// Flash attention R22: Pt-free via permuted-kv QK fragments.
// Diagnosis rebuilt from R13/R15 pair: R13 structure is ~87% LDS-port-bound
// (10.2MB DS/CU ~= 7500 cyc/tile of the 8650 wall); R15 halved traffic but
// also halved occupancy -> latency-bound at same wall. Fix that keeps 16
// waves/CU: QK's A-rows are arbitrary LDS rows, so permute kf set i to
// cover kv {8*quad + j + 4*(i&1) + 32*(i>>1)}. Then each lane's sacc IS the
// PV B-fragment: pf0 = pack(sacc[0],sacc[1]) (kv 8q..8q+7), pf1 =
// pack(sacc[2],sacc[3]) (kv 32+8q..+7). Removes per wave-ss: 4 ds_write_b64
// + 2 ds_read_b128 (-20% DS) + the lgkmcnt(0) serialization; frees Pt
// (LDS 80->64KB). Staging key for K becomes (r&3)|(((r>>3)&1)<<2), which
// makes the read-side XOR collapse to the SAME (l15&7) swz0/swz1 (2-way,
// conflict-free). V staging/reads, qf, epilogue unchanged.
// ---------------------------------------------------------------------------
__global__ __launch_bounds__(512, 4) void flash(
    const short* __restrict__ qws, const short* __restrict__ kws,
    const short* __restrict__ vtws, unsigned short* __restrict__ vals) {
  __shared__ __attribute__((aligned(16))) short Ks[2][128 * 64];
  __shared__ __attribute__((aligned(16))) short Vts[2][2][64 * 64];
  const int tid = threadIdx.x;
  const int w = tid >> 6, l = tid & 63, l15 = l & 15, quad = l >> 4;
  // XCD-affinity decode: round-robin dispatch puts b on XCD b&7. Give each
  // XCD 4 whole (h,n) pairs (all 16 of their qb blocks).
  const int b = blockIdx.x;
  const int hn = (b & 7) * 4 + (b >> 7);   // 0..31
  const int qb = (b >> 3) & 15;
  const int h = hn & 15, n = hn >> 4;
  const int nh = n * H + h;
  const short* Qh = qws + nh * S * HD;
  const short* Kh = kws + nh * S * HD;
  const short* Vth = vtws + nh * HD * S;

  const int q0 = qb * 128 + w * 16;
  short8 qf[2];
  for (int c = 0; c < 2; ++c)
    qf[c] = *(const short8*)(Qh + (q0 + l15) * HD + c * 32 + quad * 8);

  // swizzled granule offsets (shorts) for fragment reads
  const int swz0 = ((4 * 0 + quad) ^ (l15 & 7)) * 8;
  const int swz1 = ((4 * 1 + quad) ^ (l15 & 7)) * 8;
  // permuted kf row base: set i reads rows rbase + 4*(i&1) + 32*(i>>1),
  // so lane (quad, reg j) of sacc[i] holds kv = 8*quad + j + 4*(i&1) + 32*(i>>1)
  const int rbase = 8 * (l15 >> 2) + (l15 & 3);

  float lpart = 0.f;                       // per-lane partial of sum(exp2(s))
  f32x4 zero = {0.f, 0.f, 0.f, 0.f};
  f32x4 oacc[4] = {zero, zero, zero, zero};

  // DMA stage of one 128-step KV tile into buffer `buf` (swizzle via gather).
  // K uses key (r&3)|(((r>>3)&1)<<2) so permuted-row reads collapse to the
  // standard (l15&7) XOR; V keeps key (r&7).
  auto stage = [&](int kv0, int buf) {
    for (int i = 0; i < 2; ++i) {
      int u = i * 512 + tid;
      int r = u >> 3;
      int c = (u & 7) ^ ((r & 3) | (((r >> 3) & 1) << 2));
      async_ld16(Kh + (kv0 + r) * HD + c * 8, &Ks[buf][u * 8]);
    }
    for (int i = 0; i < 2; ++i) {
      int v = tid;                         // within-sub-tile chunk id
      int r = v >> 3;                      // d-row 0..63
      int c = (v & 7) ^ (r & 7);
      async_ld16(Vth + r * S + kv0 + i * 64 + c * 8, &Vts[buf][i][v * 8]);
    }
  };

  stage(0, 0);
  for (int t = 0; t < 16; ++t) {
    const int buf = t & 1;
    __syncthreads();                       // drains DMA for tile t; frees buf^1
    if (t < 15) stage((t + 1) * 128, buf ^ 1);

    for (int ss = 0; ss < 2; ++ss) {
      const short* Kb = &Ks[buf][ss * 64 * 64];
      const short* Vb = Vts[buf][ss];

      f32x4 sacc[4] = {zero, zero, zero, zero};
      {
        short8 kf[4];
        for (int i = 0; i < 4; ++i)
          kf[i] = *(const short8*)(Kb + (rbase + 4 * (i & 1) + 32 * (i >> 1)) * 64 + swz0);
        for (int i = 0; i < 4; ++i)
          sacc[i] = __builtin_amdgcn_mfma_f32_16x16x32_bf16(kf[i], qf[0], sacc[i], 0, 0, 0);
        for (int i = 0; i < 4; ++i)
          kf[i] = *(const short8*)(Kb + (rbase + 4 * (i & 1) + 32 * (i >> 1)) * 64 + swz1);
        for (int i = 0; i < 4; ++i)
          sacc[i] = __builtin_amdgcn_mfma_f32_16x16x32_bf16(kf[i], qf[1], sacc[i], 0, 0, 0);
      }

      // static-max softmax: p = 2^s; per-lane partial sum only
      for (int i = 0; i < 4; ++i) {
        f32x4 p;
        p.x = fexp2(sacc[i].x);
        p.y = fexp2(sacc[i].y);
        p.z = fexp2(sacc[i].z);
        p.w = fexp2(sacc[i].w);
        sacc[i] = p;
        lpart += p.x + p.y + p.z + p.w;
      }

      // P fragments built fully in-register (no Pt LDS round-trip):
      // pf0 = kv {8*quad..8*quad+7}, pf1 = kv {32+8*quad..+7} for q=l15.
      uint4v w0, w1;
      w0.x = pk_bf16(sacc[0].x, sacc[0].y);
      w0.y = pk_bf16(sacc[0].z, sacc[0].w);
      w0.z = pk_bf16(sacc[1].x, sacc[1].y);
      w0.w = pk_bf16(sacc[1].z, sacc[1].w);
      w1.x = pk_bf16(sacc[2].x, sacc[2].y);
      w1.y = pk_bf16(sacc[2].z, sacc[2].w);
      w1.z = pk_bf16(sacc[3].x, sacc[3].y);
      w1.w = pk_bf16(sacc[3].z, sacc[3].w);
      short8 pf0 = __builtin_bit_cast(short8, w0);
      short8 pf1 = __builtin_bit_cast(short8, w1);

      {
        short8 vf[4];
        for (int i = 0; i < 4; ++i)
          vf[i] = *(const short8*)(Vb + (i * 16 + l15) * 64 + swz0);
        for (int i = 0; i < 4; ++i)
          oacc[i] = __builtin_amdgcn_mfma_f32_16x16x32_bf16(vf[i], pf0, oacc[i], 0, 0, 0);
        for (int i = 0; i < 4; ++i)
          vf[i] = *(const short8*)(Vb + (i * 16 + l15) * 64 + swz1);
        for (int i = 0; i < 4; ++i)
          oacc[i] = __builtin_amdgcn_mfma_f32_16x16x32_bf16(vf[i], pf1, oacc[i], 0, 0, 0);
      }
    }
  }

  // final row-sum across quads, then O^T[d][q] / l -> vals[n][s][h*64+d]
  float lrun = lpart;
  lrun += __shfl_xor(lrun, 16);
  lrun += __shfl_xor(lrun, 32);
  float inv = 1.0f / lrun;
  int s = q0 + l15;
  for (int i = 0; i < 4; ++i) {
    uint2v pk;
    pk.x = pk_bf16(oacc[i].x * inv, oacc[i].y * inv);
    pk.y = pk_bf16(oacc[i].z * inv, oacc[i].w * inv);
    *(uint2v*)(vals + (n * S + s) * DM + h * HD + i * 16 + quad * 4) = pk;
  }
}

// ---------------------------------------------------------------------------
// GEMM 3 (R21-exact): 128x64 tile, 2/CU, lane-coalesced scalar epilogue,
// T2 XOR-swizzled staging/reads.
// ---------------------------------------------------------------------------
__global__ __launch_bounds__(256, 2) void gemm_out(
    const short* __restrict__ A, const short* __restrict__ W,
    float* __restrict__ out) {
  const int K = 1024;
  __shared__ __attribute__((aligned(16))) short As[128 * 64];
  __shared__ __attribute__((aligned(16))) short Bs[64 * 64];
  const int tid = threadIdx.x;
  const int w = tid >> 6, l = tid & 63, l15 = l & 15, quad = l >> 4;
  const int wm = (w >> 1) * 64, wn = (w & 1) * 32;
  const int row0 = blockIdx.y * 128, col0 = blockIdx.x * 64;

  f32x4 zero = {0.f, 0.f, 0.f, 0.f};
  f32x4 acc[4][2];
  for (int i = 0; i < 4; ++i)
    for (int j = 0; j < 2; ++j) acc[i][j] = zero;

  const short* Ag = A + row0 * K;
  const short* Bg = W + col0 * K;

  const int rs = l15 & 7;

  for (int k0 = 0; k0 < K; k0 += 64) {
    __syncthreads();
    for (int i = 0; i < 4; ++i) {
      int u = i * 256 + tid;
      int r = u >> 3, c = (u & 7) ^ (r & 7);
      async_ld16(Ag + r * K + k0 + c * 8, As + u * 8);
    }
    for (int i = 0; i < 2; ++i) {
      int u = i * 256 + tid;
      int r = u >> 3, c = (u & 7) ^ (r & 7);
      async_ld16(Bg + r * K + k0 + c * 8, Bs + u * 8);
    }
    __syncthreads();
    for (int kk = 0; kk < 2; ++kk) {
      const int slot = ((kk * 4 + quad) ^ rs) * 8;
      short8 a[4], b[2];
      for (int i = 0; i < 4; ++i)
        a[i] = *(const short8*)(As + (wm + i * 16 + l15) * 64 + slot);
      for (int j = 0; j < 2; ++j)
        b[j] = *(const short8*)(Bs + (wn + j * 16 + l15) * 64 + slot);
      for (int i = 0; i < 4; ++i)
        for (int j = 0; j < 2; ++j)
          acc[i][j] = __builtin_amdgcn_mfma_f32_16x16x32_bf16(a[i], b[j], acc[i][j], 0, 0, 0);
    }
  }

  for (int i = 0; i < 4; ++i) {
    int rowb = row0 + wm + i * 16 + quad * 4;
    for (int j = 0; j < 2; ++j) {
      int e = col0 + wn + j * 16 + l15;
      f32x4 v = acc[i][j];
      out[(rowb + 0) * 1024 + e] = v.x;
      out[(rowb + 1) * 1024 + e] = v.y;
      out[(rowb + 2) * 1024 + e] = v.z;
      out[(rowb + 3) * 1024 + e] = v.w;
    }
  }
}

extern "C" void kernel_launch(void* const* d_in, const int* in_sizes, int n_in,
                              void* d_out, int out_size, void* d_ws, size_t ws_size,
                              hipStream_t stream) {
  const float* x = (const float*)d_in[0];      // (2, 2048, 1024) fp32
  const float* qkv_w = (const float*)d_in[1];  // (3072, 1024) fp32
  const float* o_w = (const float*)d_in[2];    // (1024, 1024) fp32
  float* out = (float*)d_out;                  // fp32

  char* ws = (char*)d_ws;
  unsigned short* xb   = (unsigned short*)(ws);                   // [0, 8M)
  unsigned short* wb   = (unsigned short*)(ws + (8ull << 20));    // [8M, 14M)
  unsigned short* owb  = (unsigned short*)(ws + (14ull << 20));   // [14M, 16M)
  unsigned short* qws  = (unsigned short*)(ws + (16ull << 20));   // [16M, 24M)
  unsigned short* kws  = (unsigned short*)(ws + (24ull << 20));   // [24M, 32M)
  unsigned short* vtws = (unsigned short*)(ws + (32ull << 20));   // [32M, 40M)
  unsigned short* vals = xb;  // alias: xb dead after gemm_qkv

  convert_all<<<8192, 256, 0, stream>>>(x, qkv_w, o_w, xb, wb, owb);
  gemm_qkv<<<dim3(24, 32), 256, 0, stream>>>(
      (const short*)xb, (const short*)wb, qws, kws, vtws);
  flash<<<512, 512, 0, stream>>>(
      (const short*)qws, (const short*)kws, (const short*)vtws, vals);
  gemm_out<<<dim3(16, 32), 256, 0, stream>>>(
      (const short*)vals, (const short*)owb, out);
}